// Round 1
// baseline (261.111 us; speedup 1.0000x reference)
//
#include <hip/hip_runtime.h>

// GQA forward: out = Attn(x@Wq, x@Wk, x@Wv, causal) @ Wo
// n=2048 tokens, dmodel=2048, 32 heads x 64 dim, 8 KV groups (GQA 4:1).
// fp32 I/O, bf16 MFMA compute (harness threshold is bf16-grade).

typedef __attribute__((ext_vector_type(8))) short bf16x8;
typedef __attribute__((ext_vector_type(4))) short bf16x4;
typedef __attribute__((ext_vector_type(4))) float f32x4;

__device__ __forceinline__ short f2bf(float f) {
  unsigned u = __builtin_bit_cast(unsigned, f);
  u += 0x7FFFu + ((u >> 16) & 1u);  // RNE
  return (short)(u >> 16);
}

__device__ __forceinline__ void gload_lds16(const void* g, void* l) {
  // async global->LDS, 16B per lane; LDS dest = wave-uniform base + lane*16
  __builtin_amdgcn_global_load_lds(
      (const __attribute__((address_space(1))) unsigned int*)g,
      (__attribute__((address_space(3))) unsigned int*)l, 16, 0, 0);
}

// ---------------- fp32 -> bf16 elementwise (X) ----------------
__global__ __launch_bounds__(256) void cvtx(const float* __restrict__ x,
                                            short* __restrict__ y) {
  const int i = (blockIdx.x * 256 + threadIdx.x) * 4;
  const float4 v = *(const float4*)&x[i];
  bf16x4 r;
  r[0] = f2bf(v.x); r[1] = f2bf(v.y); r[2] = f2bf(v.z); r[3] = f2bf(v.w);
  *(bf16x4*)&y[i] = r;
}

// ------------- fp32 [R][C] -> bf16 transposed [C][R] -------------
__global__ __launch_bounds__(256) void tcvt(const float* __restrict__ src,
                                            short* __restrict__ dst,
                                            int R, int C) {
  __shared__ float t[32][33];
  const int c0 = blockIdx.x * 32, r0 = blockIdx.y * 32;
  const int tx = threadIdx.x & 31, ty = threadIdx.x >> 5;  // ty 0..7
#pragma unroll
  for (int i = 0; i < 4; ++i)
    t[ty + i * 8][tx] = src[(r0 + ty + i * 8) * C + c0 + tx];
  __syncthreads();
#pragma unroll
  for (int i = 0; i < 4; ++i)
    dst[(c0 + ty + i * 8) * R + r0 + tx] = f2bf(t[tx][ty + i * 8]);
}

// ------------- bf16 [R][ld] submatrix -> bf16 transposed [C][R] -------------
__global__ __launch_bounds__(256) void tbf(const short* __restrict__ src,
                                           short* __restrict__ dst,
                                           int R, int C, int ldsrc) {
  __shared__ short t[32][33];
  const int c0 = blockIdx.x * 32, r0 = blockIdx.y * 32;
  const int tx = threadIdx.x & 31, ty = threadIdx.x >> 5;
#pragma unroll
  for (int i = 0; i < 4; ++i)
    t[ty + i * 8][tx] = src[(r0 + ty + i * 8) * ldsrc + c0 + tx];
  __syncthreads();
#pragma unroll
  for (int i = 0; i < 4; ++i)
    dst[(c0 + ty + i * 8) * R + r0 + tx] = t[tx][ty + i * 8];
}

// ------------- bf16 GEMM: C[M][N] = A[M][K] @ B[N][K]^T -------------
// 128x128 tile, BK=32, 4 waves (2x2), 16x16x32 MFMA, global_load_lds staging.
template <int OUT_BF16>
__global__ __launch_bounds__(256) void gemm_bt(const short* __restrict__ A,
                                               const short* __restrict__ B,
                                               void* __restrict__ Cv,
                                               int M, int N, int K) {
  __shared__ short As[128 * 32];
  __shared__ short Bs[128 * 32];
  const int tid = threadIdx.x;
  const int lane = tid & 63, wid = tid >> 6;
  const int l15 = lane & 15, lg = lane >> 4;
  const int row0 = blockIdx.y * 128, col0 = blockIdx.x * 128;
  const int wr = (wid >> 1) * 64, wc = (wid & 1) * 64;
  const int ra = tid >> 2, sa = tid & 3;  // staging: row ra(+64), 8-elem seg sa
  f32x4 acc[4][4] = {};
  const short* ag = A + (row0 + ra) * K + sa * 8;
  const short* bg = B + (col0 + ra) * K + sa * 8;
  short* lA = As + wid * 512;  // wave-uniform LDS base (bytes: wid*1024)
  short* lB = Bs + wid * 512;

  for (int kk = 0; kk < K; kk += 32) {
    __syncthreads();  // prior iteration's frag reads complete
    gload_lds16(ag + kk, lA);
    gload_lds16(ag + kk + 64 * K, lA + 2048);
    gload_lds16(bg + kk, lB);
    gload_lds16(bg + kk + 64 * K, lB + 2048);
    __syncthreads();  // (compiler drains vmcnt before barrier)
    bf16x8 af[4], bfr[4];
#pragma unroll
    for (int m = 0; m < 4; ++m)
      af[m] = *(const bf16x8*)&As[(wr + m * 16 + l15) * 32 + lg * 8];
#pragma unroll
    for (int n = 0; n < 4; ++n)
      bfr[n] = *(const bf16x8*)&Bs[(wc + n * 16 + l15) * 32 + lg * 8];
#pragma unroll
    for (int m = 0; m < 4; ++m)
#pragma unroll
      for (int n = 0; n < 4; ++n)
        acc[m][n] = __builtin_amdgcn_mfma_f32_16x16x32_bf16(af[m], bfr[n],
                                                            acc[m][n], 0, 0, 0);
  }
  // epilogue: D row=(lane>>4)*4+i, col=lane&15
#pragma unroll
  for (int m = 0; m < 4; ++m)
#pragma unroll
    for (int n = 0; n < 4; ++n)
#pragma unroll
      for (int i = 0; i < 4; ++i) {
        const int r = row0 + wr + m * 16 + lg * 4 + i;
        const int c = col0 + wc + n * 16 + l15;
        if (OUT_BF16)
          ((short*)Cv)[r * N + c] = f2bf(acc[m][n][i]);
        else
          ((float*)Cv)[r * N + c] = acc[m][n][i];
      }
}

// ------------- flash attention, causal, d=64 -------------
// grid (32 q-blocks of 64 rows, 32 heads); 4 waves x 16 q-rows each.
// QKV: bf16 [2048][3072] (Q cols 0..2047, K 2048..2559, V 2560..3071)
// Vt:  bf16 [512][2048]  (per group g rows g*64..g*64+63 = V^T)
__global__ __launch_bounds__(256) void attn_fwd(const short* __restrict__ QKV,
                                                const short* __restrict__ Vt,
                                                short* __restrict__ CTX) {
  const int ldq = 3072;
  const int qb = blockIdx.x;
  const int h = blockIdx.y;
  const int g = h >> 2;
  const int tid = threadIdx.x;
  const int lane = tid & 63, wid = tid >> 6;
  const int l15 = lane & 15, lg = lane >> 4;
  const int qrow0 = qb * 64 + wid * 16;

  __shared__ short Ks[64 * 64];     // [tok][d], XOR-swizzled 16B segs
  __shared__ short Vs[64 * 64];     // [d][tok], XOR-swizzled
  __shared__ short Ps[4][16 * 64];  // per-wave P tile [q][tok], swizzled

  bf16x8 qf[2];
#pragma unroll
  for (int kc = 0; kc < 2; ++kc)
    qf[kc] = *(const bf16x8*)&QKV[(qrow0 + l15) * ldq + h * 64 + kc * 32 + lg * 8];

  float m_run[4], l_run[4];
#pragma unroll
  for (int i = 0; i < 4; ++i) { m_run[i] = -1e30f; l_run[i] = 0.f; }
  f32x4 accO[4] = {};

  const int srow = tid >> 3, sseg = tid & 7;  // staging: 64 rows x 8 segs, 2 passes
  const int ktiles = qb + 1;
  for (int kt = 0; kt < ktiles; ++kt) {
    const int tokbase = kt * 64;
    const bf16x8 k0 = *(const bf16x8*)&QKV[(tokbase + srow) * ldq + 2048 + g * 64 + sseg * 8];
    const bf16x8 k1 = *(const bf16x8*)&QKV[(tokbase + srow + 32) * ldq + 2048 + g * 64 + sseg * 8];
    const bf16x8 v0 = *(const bf16x8*)&Vt[(g * 64 + srow) * 2048 + tokbase + sseg * 8];
    const bf16x8 v1 = *(const bf16x8*)&Vt[(g * 64 + srow + 32) * 2048 + tokbase + sseg * 8];
    __syncthreads();  // previous tile's LDS reads done
    *(bf16x8*)&Ks[srow * 64 + ((sseg ^ (srow & 7)) * 8)] = k0;
    *(bf16x8*)&Ks[(srow + 32) * 64 + ((sseg ^ (srow & 7)) * 8)] = k1;
    *(bf16x8*)&Vs[srow * 64 + ((sseg ^ (srow & 7)) * 8)] = v0;
    *(bf16x8*)&Vs[(srow + 32) * 64 + ((sseg ^ (srow & 7)) * 8)] = v1;
    __syncthreads();
    if (tokbase > qrow0 + 15) continue;  // wave-uniform; both barriers already hit

    // S = (Q K^T): A=Q frag, B: lane holds K[t*16+l15][kc*32+lg*8..+8]
    f32x4 s[4];
#pragma unroll
    for (int t = 0; t < 4; ++t) {
      s[t] = (f32x4){0.f, 0.f, 0.f, 0.f};
#pragma unroll
      for (int kc = 0; kc < 2; ++kc) {
        const int krow = t * 16 + l15;
        const int kseg = kc * 4 + lg;
        const bf16x8 kf = *(const bf16x8*)&Ks[krow * 64 + ((kseg ^ (krow & 7)) * 8)];
        s[t] = __builtin_amdgcn_mfma_f32_16x16x32_bf16(qf[kc], kf, s[t], 0, 0, 0);
      }
    }
    // scale + causal mask; lane holds S[q=qrow0+lg*4+i][k=tokbase+t*16+l15]
    float p[4][4], tmax[4];
#pragma unroll
    for (int i = 0; i < 4; ++i) tmax[i] = -1e30f;
#pragma unroll
    for (int t = 0; t < 4; ++t)
#pragma unroll
      for (int i = 0; i < 4; ++i) {
        float v = s[t][i] * 0.125f;
        if (tokbase + t * 16 + l15 > qrow0 + lg * 4 + i) v = -1e30f;
        p[t][i] = v;
        tmax[i] = fmaxf(tmax[i], v);
      }
#pragma unroll
    for (int off = 1; off < 16; off <<= 1)
#pragma unroll
      for (int i = 0; i < 4; ++i)
        tmax[i] = fmaxf(tmax[i], __shfl_xor(tmax[i], off, 64));

    float alpha[4], rsum[4];
#pragma unroll
    for (int i = 0; i < 4; ++i) {
      const float mn = fmaxf(m_run[i], tmax[i]);
      alpha[i] = exp2f((m_run[i] - mn) * 1.4426950408889634f);
      m_run[i] = mn;
      rsum[i] = 0.f;
    }
#pragma unroll
    for (int t = 0; t < 4; ++t)
#pragma unroll
      for (int i = 0; i < 4; ++i) {
        const float e = exp2f((p[t][i] - m_run[i]) * 1.4426950408889634f);
        p[t][i] = e;
        rsum[i] += e;
      }
#pragma unroll
    for (int off = 1; off < 16; off <<= 1)
#pragma unroll
      for (int i = 0; i < 4; ++i) rsum[i] += __shfl_xor(rsum[i], off, 64);
#pragma unroll
    for (int i = 0; i < 4; ++i) l_run[i] = l_run[i] * alpha[i] + rsum[i];
#pragma unroll
    for (int n0 = 0; n0 < 4; ++n0)
#pragma unroll
      for (int i = 0; i < 4; ++i) accO[n0][i] *= alpha[i];

    // P (D-layout) -> per-wave LDS (bf16, swizzled) -> A-layout frags
#pragma unroll
    for (int t = 0; t < 4; ++t)
#pragma unroll
      for (int i = 0; i < 4; ++i) {
        const int prow = lg * 4 + i;
        const int pbyte = ((t * 16 + l15) * 2) ^ ((prow & 7) << 4);
        Ps[wid][prow * 64 + (pbyte >> 1)] = f2bf(p[t][i]);
      }
    // PV: A = P[q=l15][kc*32+lg*8..+8], B = V[tok][d=n0*16+l15] from Vs[d][tok]
#pragma unroll
    for (int kc = 0; kc < 2; ++kc) {
      const int aseg = kc * 4 + lg;
      const bf16x8 pa = *(const bf16x8*)&Ps[wid][l15 * 64 + ((aseg ^ (l15 & 7)) * 8)];
#pragma unroll
      for (int n0 = 0; n0 < 4; ++n0) {
        const int vrow = n0 * 16 + l15;
        const bf16x8 vb = *(const bf16x8*)&Vs[vrow * 64 + ((aseg ^ (vrow & 7)) * 8)];
        accO[n0] = __builtin_amdgcn_mfma_f32_16x16x32_bf16(pa, vb, accO[n0], 0, 0, 0);
      }
    }
  }
  // normalize + store ctx[q][h*64+d] bf16
#pragma unroll
  for (int n0 = 0; n0 < 4; ++n0)
#pragma unroll
    for (int i = 0; i < 4; ++i) {
      const float o = accO[n0][i] / l_run[i];
      CTX[(qrow0 + lg * 4 + i) * 2048 + h * 64 + n0 * 16 + l15] = f2bf(o);
    }
}

extern "C" void kernel_launch(void* const* d_in, const int* in_sizes, int n_in,
                              void* d_out, int out_size, void* d_ws, size_t ws_size,
                              hipStream_t stream) {
  (void)in_sizes; (void)n_in; (void)out_size; (void)ws_size;
  const float* x  = (const float*)d_in[0];
  const float* wq = (const float*)d_in[1];
  const float* wk = (const float*)d_in[2];
  const float* wv = (const float*)d_in[3];
  const float* wo = (const float*)d_in[4];
  float* out = (float*)d_out;

  char* ws = (char*)d_ws;
  short* Xb  = (short*)(ws);               // [2048][2048]   8 MB
  short* WT  = (short*)(ws + 8388608);     // [3072][2048]  12 MB (Wq^T|Wk^T|Wv^T)
  short* WoT = (short*)(ws + 20971520);    // [2048][2048]   8 MB
  short* QKV = (short*)(ws + 29360128);    // [2048][3072]  12 MB
  short* Vt  = (short*)(ws + 41943040);    // [512][2048]    2 MB
  short* CTX = (short*)(ws + 44040192);    // [2048][2048]   8 MB  (ends 50 MB)

  // 1. convert X to bf16
  cvtx<<<4096, 256, 0, stream>>>(x, Xb);
  // 2. transpose+convert weights to bf16 [N][K]
  { dim3 g(64, 64); tcvt<<<g, 256, 0, stream>>>(wq, WT, 2048, 2048); }
  { dim3 g(16, 64); tcvt<<<g, 256, 0, stream>>>(wk, WT + 2048 * 2048, 2048, 512); }
  { dim3 g(16, 64); tcvt<<<g, 256, 0, stream>>>(wv, WT + 2560 * 2048, 2048, 512); }
  { dim3 g(64, 64); tcvt<<<g, 256, 0, stream>>>(wo, WoT, 2048, 2048); }
  // 3. fused QKV projection: [2048,3072] = Xb @ WT^T
  { dim3 g(24, 16); gemm_bt<1><<<g, 256, 0, stream>>>(Xb, WT, QKV, 2048, 3072, 2048); }
  // 4. V^T per group for the PV step
  { dim3 g(16, 64); tbf<<<g, 256, 0, stream>>>(QKV + 2560, Vt, 2048, 512, 3072); }
  // 5. causal GQA flash attention -> CTX bf16
  { dim3 g(32, 32); attn_fwd<<<g, 256, 0, stream>>>(QKV, Vt, CTX); }
  // 6. output projection (fp32 out): out = CTX @ WoT^T
  { dim3 g(16, 16); gemm_bt<0><<<g, 256, 0, stream>>>(CTX, WoT, out, 2048, 2048, 2048); }
}

// Round 2
// 212.110 us; speedup vs baseline: 1.2310x; 1.2310x over previous
//
#include <hip/hip_runtime.h>

// GQA forward: out = Attn(x@Wq, x@Wk, x@Wv, causal) @ Wo
// n=2048 tokens, dmodel=2048, 32 heads x 64 dim, 8 KV groups (GQA 4:1).
// fp32 I/O, bf16 MFMA compute (harness threshold is bf16-grade).

typedef __attribute__((ext_vector_type(8))) short bf16x8;
typedef __attribute__((ext_vector_type(4))) short bf16x4;
typedef __attribute__((ext_vector_type(4))) float f32x4;

__device__ __forceinline__ short f2bf(float f) {
  unsigned u = __builtin_bit_cast(unsigned, f);
  u += 0x7FFFu + ((u >> 16) & 1u);  // RNE
  return (short)(u >> 16);
}

__device__ __forceinline__ void gload_lds16(const void* g, void* l) {
  __builtin_amdgcn_global_load_lds(
      (const __attribute__((address_space(1))) unsigned int*)g,
      (__attribute__((address_space(3))) unsigned int*)l, 16, 0, 0);
}

// ---------------- fp32 -> bf16 elementwise (X) ----------------
__global__ __launch_bounds__(256) void cvtx(const float* __restrict__ x,
                                            short* __restrict__ y) {
  const int i = (blockIdx.x * 256 + threadIdx.x) * 4;
  const float4 v = *(const float4*)&x[i];
  bf16x4 r;
  r[0] = f2bf(v.x); r[1] = f2bf(v.y); r[2] = f2bf(v.z); r[3] = f2bf(v.w);
  *(bf16x4*)&y[i] = r;
}

// ------------- fp32 [R][C] -> bf16 transposed [C][R] -------------
__global__ __launch_bounds__(256) void tcvt(const float* __restrict__ src,
                                            short* __restrict__ dst,
                                            int R, int C) {
  __shared__ float t[32][33];
  const int c0 = blockIdx.x * 32, r0 = blockIdx.y * 32;
  const int tx = threadIdx.x & 31, ty = threadIdx.x >> 5;
#pragma unroll
  for (int i = 0; i < 4; ++i)
    t[ty + i * 8][tx] = src[(r0 + ty + i * 8) * C + c0 + tx];
  __syncthreads();
#pragma unroll
  for (int i = 0; i < 4; ++i)
    dst[(c0 + ty + i * 8) * R + r0 + tx] = f2bf(t[tx][ty + i * 8]);
}

// ------------- bf16 [R][ld] submatrix -> bf16 transposed [C][R] -------------
__global__ __launch_bounds__(256) void tbf(const short* __restrict__ src,
                                           short* __restrict__ dst,
                                           int R, int C, int ldsrc) {
  __shared__ short t[32][33];
  const int c0 = blockIdx.x * 32, r0 = blockIdx.y * 32;
  const int tx = threadIdx.x & 31, ty = threadIdx.x >> 5;
#pragma unroll
  for (int i = 0; i < 4; ++i)
    t[ty + i * 8][tx] = src[(r0 + ty + i * 8) * ldsrc + c0 + tx];
  __syncthreads();
#pragma unroll
  for (int i = 0; i < 4; ++i)
    dst[(c0 + ty + i * 8) * R + r0 + tx] = t[tx][ty + i * 8];
}

// ------------- bf16 GEMM: C[M][N] = A[M][K] @ B[N][K]^T -------------
// 128x128 tile, BK=32, 4 waves (2x2), 16x16x32 MFMA, global_load_lds staging.
// Columns c < scale_cols of the output are multiplied by cscale (used to fold
// the attention softmax scale 0.125*log2e into Q at zero cost).
template <int OUT_BF16>
__global__ __launch_bounds__(256) void gemm_bt(const short* __restrict__ A,
                                               const short* __restrict__ B,
                                               void* __restrict__ Cv,
                                               int M, int N, int K,
                                               float cscale, int scale_cols) {
  __shared__ short As[128 * 32];
  __shared__ short Bs[128 * 32];
  const int tid = threadIdx.x;
  const int lane = tid & 63, wid = tid >> 6;
  const int l15 = lane & 15, lg = lane >> 4;
  const int row0 = blockIdx.y * 128, col0 = blockIdx.x * 128;
  const int wr = (wid >> 1) * 64, wc = (wid & 1) * 64;
  const int ra = tid >> 2, sa = tid & 3;
  f32x4 acc[4][4] = {};
  const short* ag = A + (row0 + ra) * K + sa * 8;
  const short* bg = B + (col0 + ra) * K + sa * 8;
  short* lA = As + wid * 512;
  short* lB = Bs + wid * 512;

  for (int kk = 0; kk < K; kk += 32) {
    __syncthreads();
    gload_lds16(ag + kk, lA);
    gload_lds16(ag + kk + 64 * K, lA + 2048);
    gload_lds16(bg + kk, lB);
    gload_lds16(bg + kk + 64 * K, lB + 2048);
    __syncthreads();
    bf16x8 af[4], bfr[4];
#pragma unroll
    for (int m = 0; m < 4; ++m)
      af[m] = *(const bf16x8*)&As[(wr + m * 16 + l15) * 32 + lg * 8];
#pragma unroll
    for (int n = 0; n < 4; ++n)
      bfr[n] = *(const bf16x8*)&Bs[(wc + n * 16 + l15) * 32 + lg * 8];
#pragma unroll
    for (int m = 0; m < 4; ++m)
#pragma unroll
      for (int n = 0; n < 4; ++n)
        acc[m][n] = __builtin_amdgcn_mfma_f32_16x16x32_bf16(af[m], bfr[n],
                                                            acc[m][n], 0, 0, 0);
  }
#pragma unroll
  for (int m = 0; m < 4; ++m)
#pragma unroll
    for (int n = 0; n < 4; ++n)
#pragma unroll
      for (int i = 0; i < 4; ++i) {
        const int r = row0 + wr + m * 16 + lg * 4 + i;
        const int c = col0 + wc + n * 16 + l15;
        float v = acc[m][n][i];
        if (c < scale_cols) v *= cscale;
        if (OUT_BF16)
          ((short*)Cv)[r * N + c] = f2bf(v);
        else
          ((float*)Cv)[r * N + c] = v;
      }
}

// ------------- flash attention, causal, d=64, GQA 4:1 -------------
// grid (32 q-blocks, 32 heads); 4 waves x 16 q-rows. LPT: qb = 31-blockIdx.x.
// Swapped QK^T (S^T in regs) -> lane-local softmax (q = lane&15).
// Q pre-scaled by 0.125*log2e in the QKV GEMM epilogue.
__global__ __launch_bounds__(256) void attn_fwd(const short* __restrict__ QKV,
                                                const short* __restrict__ Vt,
                                                short* __restrict__ CTX) {
  const int ldq = 3072;
  const int qb = 31 - blockIdx.x;  // longest-processing-time-first
  const int h = blockIdx.y;
  const int g = h >> 2;
  const int tid = threadIdx.x;
  const int lane = tid & 63, wid = tid >> 6;
  const int l15 = lane & 15, lg = lane >> 4;
  const int qrow0 = qb * 64 + wid * 16;

  __shared__ short Ks[2][64 * 64];  // [tok][d], XOR-swizzled 16B segs
  __shared__ short Vs[2][64 * 64];  // [d][tok], XOR-swizzled
  __shared__ short Ps[4][16 * 64];  // per-wave P^T / O^T relayout buffer

  const int swz = (l15 & 7) << 3;  // short-index XOR for Ps rows

  // Q as B-operand: lane holds Q[qrow0+l15][kc*32 + lg*8 .. +8]
  bf16x8 qf[2];
#pragma unroll
  for (int kc = 0; kc < 2; ++kc)
    qf[kc] = *(const bf16x8*)&QKV[(qrow0 + l15) * ldq + h * 64 + kc * 32 + lg * 8];

  float m_run = -3e38f, l_run = 0.f;
  f32x4 accO[4] = {};

  // staging: thread covers K/V rows srow, srow+32, 8-elem seg sseg
  const int srow = tid >> 3, sseg = tid & 7;
  const int ssw = (sseg ^ (srow & 7)) * 8;
  const short* Kg = QKV + 2048 + g * 64 + sseg * 8;
  const short* Vg = Vt + (g * 64 + srow) * 2048 + sseg * 8;
  const int ktiles = qb + 1;

  bf16x8 rk0 = *(const bf16x8*)&Kg[srow * ldq];
  bf16x8 rk1 = *(const bf16x8*)&Kg[(srow + 32) * ldq];
  bf16x8 rv0 = *(const bf16x8*)&Vg[0];
  bf16x8 rv1 = *(const bf16x8*)&Vg[32 * 2048];

  for (int kt = 0; kt < ktiles; ++kt) {
    const int buf = kt & 1;
    const int tokbase = kt * 64;
    *(bf16x8*)&Ks[buf][srow * 64 + ssw] = rk0;
    *(bf16x8*)&Ks[buf][(srow + 32) * 64 + ssw] = rk1;
    *(bf16x8*)&Vs[buf][srow * 64 + ssw] = rv0;
    *(bf16x8*)&Vs[buf][(srow + 32) * 64 + ssw] = rv1;
    if (kt + 1 < ktiles) {  // prefetch next tile; latency hides under compute
      const int nb = (kt + 1) * 64;
      rk0 = *(const bf16x8*)&Kg[(nb + srow) * ldq];
      rk1 = *(const bf16x8*)&Kg[(nb + srow + 32) * ldq];
      rv0 = *(const bf16x8*)&Vg[nb];
      rv1 = *(const bf16x8*)&Vg[32 * 2048 + nb];
    }
    __syncthreads();  // single barrier per tile (dbuf covers WAR across iters)

    // S^T tile: lane holds S[k = tokbase+t*16+lg*4+i][q = qrow0+l15]
    f32x4 s[4];
#pragma unroll
    for (int t = 0; t < 4; ++t) {
      s[t] = (f32x4){0.f, 0.f, 0.f, 0.f};
#pragma unroll
      for (int kc = 0; kc < 2; ++kc) {
        const bf16x8 kf =
            *(const bf16x8*)&Ks[buf][(t * 16 + l15) * 64 + (((kc * 4 + lg) ^ (l15 & 7)) * 8)];
        s[t] = __builtin_amdgcn_mfma_f32_16x16x32_bf16(kf, qf[kc], s[t], 0, 0, 0);
      }
    }

    float p[4][4];
    const int kq = tokbase + lg * 4 - qrow0 - l15;  // mask iff kq + t*16 + i > 0
    if (kt == qb) {  // diagonal tile only (wave-uniform branch)
#pragma unroll
      for (int t = 0; t < 4; ++t)
#pragma unroll
        for (int i = 0; i < 4; ++i)
          p[t][i] = (kq + t * 16 + i > 0) ? -3e38f : s[t][i];
    } else {
#pragma unroll
      for (int t = 0; t < 4; ++t)
#pragma unroll
        for (int i = 0; i < 4; ++i) p[t][i] = s[t][i];
    }

    // row max: in-lane tree (16) + 2 shfl across lg groups
    float tm[4];
#pragma unroll
    for (int t = 0; t < 4; ++t)
      tm[t] = fmaxf(fmaxf(p[t][0], p[t][1]), fmaxf(p[t][2], p[t][3]));
    float mloc = fmaxf(fmaxf(tm[0], tm[1]), fmaxf(tm[2], tm[3]));
    mloc = fmaxf(mloc, __shfl_xor(mloc, 16));
    mloc = fmaxf(mloc, __shfl_xor(mloc, 32));

    const float mnew = fmaxf(m_run, mloc);
    const float alpha = exp2f(m_run - mnew);
    m_run = mnew;

    float ts[4];
#pragma unroll
    for (int t = 0; t < 4; ++t) {
      float e0 = exp2f(p[t][0] - mnew), e1 = exp2f(p[t][1] - mnew);
      float e2 = exp2f(p[t][2] - mnew), e3 = exp2f(p[t][3] - mnew);
      p[t][0] = e0; p[t][1] = e1; p[t][2] = e2; p[t][3] = e3;
      ts[t] = (e0 + e1) + (e2 + e3);
    }
    float rs = (ts[0] + ts[1]) + (ts[2] + ts[3]);
    rs += __shfl_xor(rs, 16);
    rs += __shfl_xor(rs, 32);
    l_run = l_run * alpha + rs;
#pragma unroll
    for (int t2 = 0; t2 < 4; ++t2)
#pragma unroll
      for (int i = 0; i < 4; ++i) accO[t2][i] *= alpha;

    // P^T -> per-wave LDS (packed b64 writes, swizzled rows)
#pragma unroll
    for (int t = 0; t < 4; ++t) {
      bf16x4 w;
      w[0] = f2bf(p[t][0]); w[1] = f2bf(p[t][1]);
      w[2] = f2bf(p[t][2]); w[3] = f2bf(p[t][3]);
      *(bf16x4*)&Ps[wid][l15 * 64 + ((t * 16 + lg * 4) ^ swz)] = w;
    }
    // O^T += V^T P^T : A = V^T frag, B = P^T frag
#pragma unroll
    for (int kc = 0; kc < 2; ++kc) {
      const bf16x8 pb =
          *(const bf16x8*)&Ps[wid][l15 * 64 + ((kc * 32 + lg * 8) ^ swz)];
#pragma unroll
      for (int t2 = 0; t2 < 4; ++t2) {
        const bf16x8 vb =
            *(const bf16x8*)&Vs[buf][(t2 * 16 + l15) * 64 + (((kc * 4 + lg) ^ (l15 & 7)) * 8)];
        accO[t2] = __builtin_amdgcn_mfma_f32_16x16x32_bf16(vb, pb, accO[t2], 0, 0, 0);
      }
    }
  }

  // epilogue: normalize, transpose O^T->O through Ps, coalesced 16B stores
  const float inv = 1.0f / l_run;
#pragma unroll
  for (int t2 = 0; t2 < 4; ++t2) {
    bf16x4 w;
#pragma unroll
    for (int i = 0; i < 4; ++i) w[i] = f2bf(accO[t2][i] * inv);
    *(bf16x4*)&Ps[wid][l15 * 64 + ((t2 * 16 + lg * 4) ^ swz)] = w;
  }
#pragma unroll
  for (int r = 0; r < 2; ++r) {
    const int seg = lg + r * 4;
    const bf16x8 row = *(const bf16x8*)&Ps[wid][l15 * 64 + ((seg * 8) ^ swz)];
    *(bf16x8*)&CTX[(qrow0 + l15) * 2048 + h * 64 + seg * 8] = row;
  }
}

extern "C" void kernel_launch(void* const* d_in, const int* in_sizes, int n_in,
                              void* d_out, int out_size, void* d_ws, size_t ws_size,
                              hipStream_t stream) {
  (void)in_sizes; (void)n_in; (void)out_size; (void)ws_size;
  const float* x  = (const float*)d_in[0];
  const float* wq = (const float*)d_in[1];
  const float* wk = (const float*)d_in[2];
  const float* wv = (const float*)d_in[3];
  const float* wo = (const float*)d_in[4];
  float* out = (float*)d_out;

  char* ws = (char*)d_ws;
  short* Xb  = (short*)(ws);               // [2048][2048]   8 MB
  short* WT  = (short*)(ws + 8388608);     // [3072][2048]  12 MB (Wq^T|Wk^T|Wv^T)
  short* WoT = (short*)(ws + 20971520);    // [2048][2048]   8 MB
  short* QKV = (short*)(ws + 29360128);    // [2048][3072]  12 MB
  short* Vt  = (short*)(ws + 41943040);    // [512][2048]    2 MB
  short* CTX = (short*)(ws + 44040192);    // [2048][2048]   8 MB  (ends 50 MB)

  const float qscale = 0.125f * 1.4426950408889634f;  // 1/sqrt(64) * log2(e)

  cvtx<<<4096, 256, 0, stream>>>(x, Xb);
  { dim3 g(64, 64); tcvt<<<g, 256, 0, stream>>>(wq, WT, 2048, 2048); }
  { dim3 g(16, 64); tcvt<<<g, 256, 0, stream>>>(wk, WT + 2048 * 2048, 2048, 512); }
  { dim3 g(16, 64); tcvt<<<g, 256, 0, stream>>>(wv, WT + 2560 * 2048, 2048, 512); }
  { dim3 g(64, 64); tcvt<<<g, 256, 0, stream>>>(wo, WoT, 2048, 2048); }
  // QKV projection; Q columns pre-scaled for softmax
  { dim3 g(24, 16); gemm_bt<1><<<g, 256, 0, stream>>>(Xb, WT, QKV, 2048, 3072, 2048, qscale, 2048); }
  { dim3 g(16, 64); tbf<<<g, 256, 0, stream>>>(QKV + 2560, Vt, 2048, 512, 3072); }
  { dim3 g(32, 32); attn_fwd<<<g, 256, 0, stream>>>(QKV, Vt, CTX); }
  { dim3 g(16, 16); gemm_bt<0><<<g, 256, 0, stream>>>(CTX, WoT, out, 2048, 2048, 2048, 1.0f, 0); }
}